// Round 16
// baseline (450.908 us; speedup 1.0000x reference)
//
#include <hip/hip_runtime.h>
#include <math.h>

#define N_NODES 50000
#define N_EDGES 800000
#define NGRAPHS 50
#define NHEADS 3
#define EPS 1e-5f
#define NWIN 196      // fine windows of 256 nodes: win = dst >> 8
#define WSH 8

typedef _Float16 half8 __attribute__((ext_vector_type(8)));
typedef _Float16 half2v __attribute__((ext_vector_type(2)));
typedef float f32x4 __attribute__((ext_vector_type(4)));

__device__ inline half2v h2_shfl_xor(half2v v, int m) {
  int xi = __shfl_xor(*(int*)&v, m, 64);
  return *(half2v*)&xi;
}

// ------------------------------------------------------------------ setup (+folded scalars)
__global__ void __launch_bounds__(256) k_zero_setup(int* cnt, float* gsum, float* gcnt,
                                                    float* part, float* partq,
                                                    const float* dh, int nbins, float* scal) {
  int gid = blockIdx.x * 256 + threadIdx.x;
  int gs = gridDim.x * 256;
  for (int i = gid; i < N_NODES; i += gs) cnt[i] = 0;
  for (int i = gid; i < NGRAPHS * 64; i += gs) gsum[i] = 0.f;
  for (int i = gid; i < NGRAPHS; i += gs) gcnt[i] = 0.f;
  for (int i = gid; i < 3 * 128 * 64; i += gs) { part[i] = 0.f; partq[i] = 0.f; }
  if (blockIdx.x == 0 && threadIdx.x < 64) {
    int t = threadIdx.x;
    float v = (t < nbins) ? dh[t] : 0.f;
    float lv = logf((float)t + 1.f) * v;
    float bv = (float)t * v;
    for (int d = 32; d > 0; d >>= 1) {
      v  += __shfl_down(v,  d, 64);
      lv += __shfl_down(lv, d, 64);
      bv += __shfl_down(bv, d, 64);
    }
    if (t == 0) { scal[0] = lv / v; scal[1] = bv / v; }  // avg_log, avg_lin
  }
}

__global__ void __launch_bounds__(256) k_hist(const int* __restrict__ dst, int* __restrict__ cnt) {
  int e = blockIdx.x * 256 + threadIdx.x;
  if (e < N_EDGES) atomicAdd(&cnt[dst[e]], 1);
}

__global__ void __launch_bounds__(256) k_scan_a(const int* __restrict__ cnt, int* __restrict__ off,
                                                int* __restrict__ blksum) {
  __shared__ int lds[256];
  int t = threadIdx.x;
  int base = blockIdx.x * 1024 + t * 4;
  int v0 = (base + 0 < N_NODES) ? cnt[base + 0] : 0;
  int v1 = (base + 1 < N_NODES) ? cnt[base + 1] : 0;
  int v2 = (base + 2 < N_NODES) ? cnt[base + 2] : 0;
  int v3 = (base + 3 < N_NODES) ? cnt[base + 3] : 0;
  int tsum = v0 + v1 + v2 + v3;
  lds[t] = tsum; __syncthreads();
  for (int d = 1; d < 256; d <<= 1) {
    int x = (t >= d) ? lds[t - d] : 0;
    __syncthreads();
    lds[t] += x;
    __syncthreads();
  }
  int run = lds[t] - tsum;
  if (base + 0 < N_NODES) off[base + 0] = run; run += v0;
  if (base + 1 < N_NODES) off[base + 1] = run; run += v1;
  if (base + 2 < N_NODES) off[base + 2] = run; run += v2;
  if (base + 3 < N_NODES) off[base + 3] = run;
  if (t == 255) blksum[blockIdx.x] = lds[255];
}

__global__ void __launch_bounds__(64) k_scan_b(const int* __restrict__ blksum, int* __restrict__ blkoff) {
  int t = threadIdx.x;
  int own = (t < 49) ? blksum[t] : 0;
  int v = own;
  for (int d = 1; d < 64; d <<= 1) {
    int u = __shfl_up(v, d, 64);
    if (t >= d) v += u;
  }
  if (t < 49) blkoff[t] = v - own;
}

__global__ void __launch_bounds__(256) k_scan_c(int* __restrict__ off, const int* __restrict__ blkoff,
                                                int* __restrict__ wincur) {
  int i = blockIdx.x * 256 + threadIdx.x;
  if (i < N_NODES) {
    int fo = off[i] + blkoff[i >> 10];
    off[i] = fo;
    if ((i & 255) == 0) wincur[i >> WSH] = fo;
  }
  if (i == 0) off[N_NODES] = N_EDGES;
}

// ---------------- phase 1: LDS-compact partition into 196 fine windows ----------------
__global__ void __launch_bounds__(256) k_part1(const int* __restrict__ src, const int* __restrict__ dst,
                                               int* __restrict__ wincur, int* __restrict__ pairS,
                                               unsigned char* __restrict__ pairDL) {
  __shared__ int hist[256];
  __shared__ int scan[256];
  __shared__ int baseg[256];
  __shared__ int place[256];
  __shared__ int sS[2048];
  __shared__ unsigned char sDL[2048];
  __shared__ unsigned char sW[2048];
  int t = threadIdx.x;
  int base = blockIdx.x * 2048;
  hist[t] = 0;
  __syncthreads();
  int d[8], s[8];
  #pragma unroll
  for (int i = 0; i < 8; ++i) {
    int e = base + t + 256 * i;
    bool val = e < N_EDGES;
    d[i] = val ? dst[e] : -1;
    s[i] = val ? src[e] : 0;
    if (val) atomicAdd(&hist[d[i] >> WSH], 1);
  }
  __syncthreads();
  int v = hist[t];
  scan[t] = v; __syncthreads();
  for (int dd = 1; dd < 256; dd <<= 1) {
    int x = (t >= dd) ? scan[t - dd] : 0;
    __syncthreads();
    scan[t] += x;
    __syncthreads();
  }
  place[t] = scan[t] - v;
  if (v > 0) baseg[t] = atomicAdd(&wincur[t], v);
  __syncthreads();
  #pragma unroll
  for (int i = 0; i < 8; ++i) {
    if (d[i] >= 0) {
      int w = d[i] >> WSH;
      int p = atomicAdd(&place[w], 1);
      sS[p] = s[i] << 7;           // byte offset into B [N,64] fp16 (128 B rows)
      sDL[p] = (unsigned char)(d[i] & 255);
      sW[p] = (unsigned char)w;
    }
  }
  __syncthreads();
  int tot = min(N_EDGES - base, 2048);
  for (int i = t; i < tot; i += 256) {
    int w = sW[i];
    int gidx = baseg[w] + (i - (scan[w] - hist[w]));
    pairS[gidx] = sS[i];
    pairDL[gidx] = sDL[i];
  }
}

// ---------------- phase 2: per-window LDS-resident CSR scatter, coalesced flush ----------------
__global__ void __launch_bounds__(256) k_part2(const int* __restrict__ off, const int* __restrict__ pairS,
                                               const unsigned char* __restrict__ pairDL,
                                               int* __restrict__ esrc) {
  __shared__ int curW[256];
  __shared__ int offW[257];
  __shared__ int esrcW[6144];
  int w = blockIdx.x, t = threadIdx.x;
  int n0 = w << WSH;
  offW[t] = off[min(n0 + t, N_NODES)];
  if (t == 0) offW[256] = off[min(n0 + 256, N_NODES)];
  curW[t] = 0;
  __syncthreads();
  int start = offW[0];
  int end = offW[256];
  int cnt = end - start;
  if (cnt <= 6144) {
    for (int i = t; i < cnt; i += 256) {
      int s = pairS[start + i];
      int dl = pairDL[start + i];
      int pos = offW[dl] - start + atomicAdd(&curW[dl], 1);
      esrcW[pos] = s;
    }
    __syncthreads();
    for (int i = t; i < cnt; i += 256) esrc[start + i] = esrcW[i];
  } else {
    for (int i = t; i < cnt; i += 256) {
      int s = pairS[start + i];
      int dl = pairDL[start + i];
      int pos = offW[dl] + atomicAdd(&curW[dl], 1);
      esrc[pos] = s;
    }
  }
}

// ------------------------------------------------------------------ f2h + weight packing (b-frag order)
__global__ void __launch_bounds__(256) k_prep(const float* __restrict__ xin, _Float16* __restrict__ xout,
                                              const float* __restrict__ preW, const float* __restrict__ postW,
                                              const float* __restrict__ linW, _Float16* __restrict__ preP,
                                              _Float16* __restrict__ postAP, _Float16* __restrict__ postBP,
                                              _Float16* __restrict__ linP) {
  int t0 = blockIdx.x * 256 + threadIdx.x;
  if (t0 < 400000) {
    const float* s = xin + (size_t)t0 * 8;
    float4 v0 = *(const float4*)s;
    float4 v1 = *(const float4*)(s + 4);
    half8 h = {(_Float16)v0.x, (_Float16)v0.y, (_Float16)v0.z, (_Float16)v0.w,
               (_Float16)v1.x, (_Float16)v1.y, (_Float16)v1.z, (_Float16)v1.w};
    *(half8*)(xout + (size_t)t0 * 8) = h;
    return;
  }
  int t = t0 - 400000;
  if (t < 24576) {  // preP: 3 * 8192
    int l = t >> 13, r = t & 8191;
    int j = r & 7, lane = (r >> 3) & 63, ctg = (r >> 9) & 7, kc = r >> 12;
    int k = kc * 32 + ((lane >> 4) << 3) + j;
    int col = ctg * 16 + (lane & 15);
    const float* W = preW + (size_t)l * 8192;
    float v = (col < 64) ? W[k * 64 + col] : W[(64 + k) * 64 + (col - 64)];
    preP[(size_t)l * 8192 + r] = (_Float16)v;
  } else if (t < 221184) {  // postAP: 3 * 65536 (aggr K plain order: mean|min|max|std)
    int q = t - 24576;
    int l = q >> 16, r = q & 65535;
    int j = r & 7, lane = (r >> 3) & 63, ct = (r >> 9) & 3, s = (r >> 11) & 3, kc = r >> 13;
    int k = kc * 32 + ((lane >> 4) << 3) + j;
    int col = ct * 16 + (lane & 15);
    postAP[(size_t)l * 65536 + r] = (_Float16)postW[(size_t)l * 69632 + (size_t)(64 + s * 256 + k) * 64 + col];
  } else if (t < 233472) {  // postBP: 3 * 4096
    int q = t - 221184;
    int l = q >> 12, r = q & 4095;
    int j = r & 7, lane = (r >> 3) & 63, ct = (r >> 9) & 3, kc = r >> 11;
    int k = kc * 32 + ((lane >> 4) << 3) + j;
    int col = ct * 16 + (lane & 15);
    postBP[(size_t)l * 4096 + r] = (_Float16)postW[(size_t)l * 69632 + (size_t)k * 64 + col];
  } else if (t < 245760) {  // linP: 3 * 4096
    int q = t - 233472;
    int l = q >> 12, r = q & 4095;
    int j = r & 7, lane = (r >> 3) & 63, ct = (r >> 9) & 3, kc = r >> 11;
    int k = kc * 32 + ((lane >> 4) << 3) + j;
    int col = ct * 16 + (lane & 15);
    linP[(size_t)l * 4096 + r] = (_Float16)linW[(size_t)l * 4096 + (size_t)k * 64 + col];
  }
}

// ------------------------------------------------------------------ GEMM1 (+fused BN coefficient computation
// from per-layer part/partq + BN-apply of previous layer). Writes A [N,64] and B [N,64].
__global__ void __launch_bounds__(256) k_mfma_g1(const _Float16* __restrict__ yin,
                                                 const float* __restrict__ part, const float* __restrict__ partq,
                                                 const float* __restrict__ bng, const float* __restrict__ bnb,
                                                 int applyBN,
                                                 const _Float16* __restrict__ wp, const float* __restrict__ bias,
                                                 _Float16* __restrict__ Aout, _Float16* __restrict__ Bout,
                                                 _Float16* __restrict__ xout) {
  __shared__ float ls[256], lq[256];
  __shared__ __align__(16) float scS[64], shS[64];
  int t = threadIdx.x, lane = t & 63, wave = t >> 6;
  int r0 = blockIdx.x * 64;
  int mrow = lane & 15, q8 = ((lane >> 4) << 3);
  if (applyBN) {
    int col = t & 63, qtr = t >> 6;
    float s = 0.f, q = 0.f;
    for (int i = 0; i < 32; ++i) {
      int slot = qtr * 32 + i;
      s += part[slot * 64 + col];
      q += partq[slot * 64 + col];
    }
    ls[t] = s; lq[t] = q; __syncthreads();
    if (t < 64) {
      s = ls[t] + ls[64 + t] + ls[128 + t] + ls[192 + t];
      q = lq[t] + lq[64 + t] + lq[128 + t] + lq[192 + t];
      float m = s / (float)N_NODES;
      float v = fmaxf(q / (float)N_NODES - m * m, 0.f);
      float sc = bng[t] * rsqrtf(v + EPS);
      scS[t] = sc;
      shS[t] = bnb[t] - m * sc;
    }
    __syncthreads();
  }
  f32x4 acc[4][2];
  #pragma unroll
  for (int rt = 0; rt < 4; ++rt) { acc[rt][0] = (f32x4)0.f; acc[rt][1] = (f32x4)0.f; }
  #pragma unroll
  for (int kc = 0; kc < 2; ++kc) {
    int k0 = kc * 32 + q8;
    half8 a[4];
    #pragma unroll
    for (int rt = 0; rt < 4; ++rt) {
      int r = min(r0 + rt * 16 + mrow, N_NODES - 1);
      a[rt] = *(const half8*)(yin + (size_t)r * 64 + k0);
    }
    if (applyBN) {
      float4 sc0 = *(const float4*)(scS + k0);
      float4 sc1 = *(const float4*)(scS + k0 + 4);
      float4 sh0 = *(const float4*)(shS + k0);
      float4 sh1 = *(const float4*)(shS + k0 + 4);
      #pragma unroll
      for (int rt = 0; rt < 4; ++rt) {
        half8 v = a[rt];
        v[0] = (_Float16)fmaxf((float)v[0] * sc0.x + sh0.x, 0.f);
        v[1] = (_Float16)fmaxf((float)v[1] * sc0.y + sh0.y, 0.f);
        v[2] = (_Float16)fmaxf((float)v[2] * sc0.z + sh0.z, 0.f);
        v[3] = (_Float16)fmaxf((float)v[3] * sc0.w + sh0.w, 0.f);
        v[4] = (_Float16)fmaxf((float)v[4] * sc1.x + sh1.x, 0.f);
        v[5] = (_Float16)fmaxf((float)v[5] * sc1.y + sh1.y, 0.f);
        v[6] = (_Float16)fmaxf((float)v[6] * sc1.z + sh1.z, 0.f);
        v[7] = (_Float16)fmaxf((float)v[7] * sc1.w + sh1.w, 0.f);
        a[rt] = v;
      }
      if (wave == 0) {
        #pragma unroll
        for (int rt = 0; rt < 4; ++rt) {
          int r = min(r0 + rt * 16 + mrow, N_NODES - 1);
          *(half8*)(xout + (size_t)r * 64 + k0) = a[rt];
        }
      }
    }
    #pragma unroll
    for (int ci = 0; ci < 2; ++ci) {
      int ctg = wave * 2 + ci;
      half8 b = *(const half8*)(wp + (size_t)((kc * 8 + ctg) * 64 + lane) * 8);
      #pragma unroll
      for (int rt = 0; rt < 4; ++rt)
        acc[rt][ci] = __builtin_amdgcn_mfma_f32_16x16x32_f16(a[rt], b, acc[rt][ci], 0, 0, 0);
    }
  }
  #pragma unroll
  for (int ci = 0; ci < 2; ++ci) {
    int col = (wave * 2 + ci) * 16 + mrow;
    bool isA = col < 64;
    float bv = isA ? bias[col] : 0.f;
    _Float16* outp = isA ? (Aout + col) : (Bout + (col - 64));
    #pragma unroll
    for (int rt = 0; rt < 4; ++rt)
      #pragma unroll
      for (int reg = 0; reg < 4; ++reg) {
        int row = r0 + rt * 16 + ((lane >> 4) << 2) + reg;
        if (row < N_NODES) outp[(size_t)row * 64] = (_Float16)(acc[rt][ci][reg] + bv);
      }
  }
}

// ------------------------------------------------------------------ aggregation: single pass, full 64 features
// XCD-ALIGNED TILING: all 16 blocks producing a 64-node tile T run on XCD T%8 —
// the same XCD where k_mfma_g23 block T consumes it. Grid = 784 tiles * 16 = 12544.
// 32 lanes/edge x 2 packed features; fully predicated 16-edge-wide loop.
__global__ void __launch_bounds__(256) k_aggr(const _Float16* __restrict__ A, const _Float16* __restrict__ B,
                                              const int* __restrict__ off, const int* __restrict__ esrc,
                                              const float* __restrict__ scal, _Float16* __restrict__ aggr,
                                              float4* __restrict__ scales) {
  int wave = threadIdx.x >> 6, lane = threadIdx.x & 63;
  int j = blockIdx.x;
  int c = j & 7;                       // XCD (dispatch round-robin heuristic)
  int k = j >> 3;                      // per-XCD sequence
  int tile = ((k >> 4) << 3) + c;      // 64-node tile, tile % 8 == c
  int n = tile * 64 + ((k & 15) << 2) + wave;
  if (n >= N_NODES) return;
  int lh = lane & 31, eg = lane >> 5;
  half2v c2 = *(const half2v*)(A + (size_t)n * 64 + lh * 2);
  int e0 = __builtin_amdgcn_readfirstlane(off[n]);
  int e1 = __builtin_amdgcn_readfirstlane(off[n + 1]);
  int deg = e1 - e0;
  const char* Bb = (const char*)B;
  int lo4 = lh * 4;
  const _Float16 HMAX = (_Float16)65504.f;
  half2v z2 = {(_Float16)0.f, (_Float16)0.f};
  half2v p2 = {HMAX, HMAX};
  half2v m2v = {-HMAX, -HMAX};
  half2v s2 = z2, q2 = z2, mn2 = p2, mx2 = m2v;
  if (deg > 0) {
    int e1m1 = e1 - 1;
    for (int e = e0; e < e1; e += 16) {
      int ro[8];
      #pragma unroll
      for (int g = 0; g < 8; ++g)
        ro[g] = esrc[min(e + g * 2 + eg, e1m1)];
      half2v v[8];
      #pragma unroll
      for (int g = 0; g < 8; ++g)
        v[g] = *(const half2v*)(Bb + ro[g] + lo4);
      #pragma unroll
      for (int g = 0; g < 8; ++g) {
        bool valid = (e + g * 2 + eg) < e1;
        half2v vm = valid ? v[g] : z2;
        s2 += vm;
        q2 += vm * vm;
        mn2 = __builtin_elementwise_min(mn2, valid ? v[g] : p2);
        mx2 = __builtin_elementwise_max(mx2, valid ? v[g] : m2v);
      }
    }
  }
  s2 += h2_shfl_xor(s2, 32);
  q2 += h2_shfl_xor(q2, 32);
  mn2 = __builtin_elementwise_min(mn2, h2_shfl_xor(mn2, 32));
  mx2 = __builtin_elementwise_max(mx2, h2_shfl_xor(mx2, 32));
  if (eg == 0) {
    _Float16* arow = aggr + (size_t)n * 256;
    half2v w;
    if (deg == 0) {
      w = z2;
      *(half2v*)(arow + lh * 2) = w;
      *(half2v*)(arow + 64 + lh * 2) = w;
      *(half2v*)(arow + 128 + lh * 2) = w;
      w[0] = (_Float16)sqrtf(EPS); w[1] = w[0];
      *(half2v*)(arow + 192 + lh * 2) = w;
    } else {
      float c0 = (float)c2[0], c1 = (float)c2[1];
      float inv = 1.f / (float)deg;
      float mb0 = (float)s2[0] * inv, mb1 = (float)s2[1] * inv;
      float v0 = fmaxf((float)q2[0] * inv - mb0 * mb0, 0.f);
      float v1 = fmaxf((float)q2[1] * inv - mb1 * mb1, 0.f);
      w[0] = (_Float16)(c0 + mb0); w[1] = (_Float16)(c1 + mb1);
      *(half2v*)(arow + lh * 2) = w;
      w[0] = (_Float16)(c0 + (float)mn2[0]); w[1] = (_Float16)(c1 + (float)mn2[1]);
      *(half2v*)(arow + 64 + lh * 2) = w;
      w[0] = (_Float16)(c0 + (float)mx2[0]); w[1] = (_Float16)(c1 + (float)mx2[1]);
      *(half2v*)(arow + 128 + lh * 2) = w;
      w[0] = (_Float16)sqrtf(v0 + EPS); w[1] = (_Float16)sqrtf(v1 + EPS);
      *(half2v*)(arow + 192 + lh * 2) = w;
    }
    if (lane == 0) {
      float degf = fmaxf((float)deg, 1.f);
      float ld = logf(degf + 1.f);
      float al = scal[0], av = scal[1];
      scales[n] = make_float4(ld / al, al / ld, degf / av, 0.f);
    }
  }
}

// ------------------------------------------------------------------ FUSED GEMM2 + GEMM3 (+BN partial stats)
__global__ void __launch_bounds__(256) k_mfma_g23(const _Float16* __restrict__ aggr,
                                                  const _Float16* __restrict__ x16,
                                                  const _Float16* __restrict__ wpA, const _Float16* __restrict__ wpB,
                                                  const float* __restrict__ postb, const float4* __restrict__ scales,
                                                  const _Float16* __restrict__ linP, const float* __restrict__ linb,
                                                  _Float16* __restrict__ y16,
                                                  float* __restrict__ part, float* __restrict__ partq) {
  __shared__ _Float16 yS[64][72];
  int t = threadIdx.x, lane = t & 63, ct = t >> 6;
  int r0 = blockIdx.x * 64;
  int mrow = lane & 15, q8 = ((lane >> 4) << 3);
  f32x4 acc[4][4];  // [rowtile][set]
  #pragma unroll
  for (int rt = 0; rt < 4; ++rt)
    #pragma unroll
    for (int s = 0; s < 4; ++s) acc[rt][s] = (f32x4)0.f;
  #pragma unroll 2
  for (int kc = 0; kc < 8; ++kc) {
    half8 a[4];
    #pragma unroll
    for (int rt = 0; rt < 4; ++rt) {
      int r = min(r0 + rt * 16 + mrow, N_NODES - 1);
      a[rt] = *(const half8*)(aggr + (size_t)r * 256 + kc * 32 + q8);  // XCD-local L2 hit
    }
    #pragma unroll
    for (int s = 0; s < 4; ++s) {
      half8 b = *(const half8*)(wpA + (size_t)((((kc * 4 + s) * 4 + ct) * 64) + lane) * 8);
      #pragma unroll
      for (int rt = 0; rt < 4; ++rt)
        acc[rt][s] = __builtin_amdgcn_mfma_f32_16x16x32_f16(a[rt], b, acc[rt][s], 0, 0, 0);
    }
  }
  #pragma unroll
  for (int kc = 0; kc < 2; ++kc) {
    half8 a[4];
    #pragma unroll
    for (int rt = 0; rt < 4; ++rt) {
      int r = min(r0 + rt * 16 + mrow, N_NODES - 1);
      a[rt] = *(const half8*)(x16 + (size_t)r * 64 + kc * 32 + q8);
    }
    half8 b = *(const half8*)(wpB + (size_t)(((kc * 4 + ct) * 64) + lane) * 8);
    #pragma unroll
    for (int rt = 0; rt < 4; ++rt)
      acc[rt][0] = __builtin_amdgcn_mfma_f32_16x16x32_f16(a[rt], b, acc[rt][0], 0, 0, 0);
  }
  int col = ct * 16 + mrow;
  float pb = postb[col];
  #pragma unroll
  for (int rt = 0; rt < 4; ++rt)
    #pragma unroll
    for (int reg = 0; reg < 4; ++reg) {
      int rr = rt * 16 + ((lane >> 4) << 2) + reg;
      int row = min(r0 + rr, N_NODES - 1);
      float4 sc = scales[row];
      float v = acc[rt][0][reg] + sc.x * acc[rt][1][reg] + sc.y * acc[rt][2][reg] + sc.z * acc[rt][3][reg] + pb;
      yS[rr][col] = (_Float16)v;
    }
  __syncthreads();
  // ---- GEMM3 from LDS
  f32x4 acc2[4];
  #pragma unroll
  for (int rt = 0; rt < 4; ++rt) acc2[rt] = (f32x4)0.f;
  #pragma unroll
  for (int kc = 0; kc < 2; ++kc) {
    half8 a[4];
    #pragma unroll
    for (int rt = 0; rt < 4; ++rt)
      a[rt] = *(const half8*)(&yS[rt * 16 + mrow][kc * 32 + q8]);
    half8 b = *(const half8*)(linP + (size_t)(((kc * 4 + ct) * 64) + lane) * 8);
    #pragma unroll
    for (int rt = 0; rt < 4; ++rt)
      acc2[rt] = __builtin_amdgcn_mfma_f32_16x16x32_f16(a[rt], b, acc2[rt], 0, 0, 0);
  }
  float bv = linb[col];
  float s = 0.f, q = 0.f;
  #pragma unroll
  for (int rt = 0; rt < 4; ++rt)
    #pragma unroll
    for (int reg = 0; reg < 4; ++reg) {
      int row = r0 + rt * 16 + ((lane >> 4) << 2) + reg;
      if (row < N_NODES) {
        float v = acc2[rt][reg] + bv;
        y16[(size_t)row * 64 + col] = (_Float16)v;
        s += v; q += v * v;
      }
    }
  int slot = (blockIdx.x & 127) * 64 + col;
  atomicAdd(&part[slot], s);
  atomicAdd(&partq[slot], q);
}

// ------------------------------------------------------------------ pooling (+fused BN coeffs + final BN)
__global__ void __launch_bounds__(256) k_pool(const _Float16* __restrict__ y16,
                                              const float* __restrict__ part, const float* __restrict__ partq,
                                              const float* __restrict__ bng, const float* __restrict__ bnb,
                                              const int* __restrict__ batch,
                                              float* __restrict__ gsum, float* __restrict__ gcnt) {
  __shared__ float ls[256], lq[256];
  __shared__ float scS[64], shS[64];
  int t = threadIdx.x, col = t & 63, rl = t >> 6;
  {
    float s = 0.f, q = 0.f;
    for (int i = 0; i < 32; ++i) {
      int slot = rl * 32 + i;
      s += part[slot * 64 + col];
      q += partq[slot * 64 + col];
    }
    ls[t] = s; lq[t] = q; __syncthreads();
    if (t < 64) {
      s = ls[t] + ls[64 + t] + ls[128 + t] + ls[192 + t];
      q = lq[t] + lq[64 + t] + lq[128 + t] + lq[192 + t];
      float m = s / (float)N_NODES;
      float v = fmaxf(q / (float)N_NODES - m * m, 0.f);
      float sc = bng[t] * rsqrtf(v + EPS);
      scS[t] = sc;
      shS[t] = bnb[t] - m * sc;
    }
    __syncthreads();
  }
  float sc = scS[col], sh = shS[col];
  int rbeg = blockIdx.x * 64 + rl * 16;
  int rend = min(rbeg + 16, N_NODES);
  int curg = -1, cr = 0;
  float acc = 0.f;
  for (int r = rbeg; r < rend; ++r) {
    int g = batch[r];
    if (g != curg) {
      if (curg >= 0) {
        atomicAdd(&gsum[curg * 64 + col], acc);
        if (col == 0) atomicAdd(&gcnt[curg], (float)cr);
      }
      curg = g; acc = 0.f; cr = 0;
    }
    acc += fmaxf((float)y16[(size_t)r * 64 + col] * sc + sh, 0.f); cr++;
  }
  if (curg >= 0) {
    atomicAdd(&gsum[curg * 64 + col], acc);
    if (col == 0) atomicAdd(&gcnt[curg], (float)cr);
  }
}

// ------------------------------------------------------------------ shared MLP + heads fused
__global__ void __launch_bounds__(64) k_sharedheads(const float* __restrict__ gsum, const float* __restrict__ gcnt,
                                                    const float* __restrict__ W, const float* __restrict__ b,
                                                    const float* __restrict__ hW1, const float* __restrict__ hb1,
                                                    const float* __restrict__ hW2, const float* __restrict__ hb2,
                                                    const float* __restrict__ hW3, const float* __restrict__ hb3,
                                                    float* __restrict__ out) {
  __shared__ float gm[64], gv[64], h1[50], h2[25];
  int bid = blockIdx.x;
  int g = bid / NHEADS, h = bid % NHEADS;
  int t = threadIdx.x;
  float cv = fmaxf(gcnt[g], 1.f);
  gm[t] = gsum[g * 64 + t] / cv;
  __syncthreads();
  float s0 = b[t];
  for (int k = 0; k < 64; ++k) s0 += gm[k] * W[k * 64 + t];
  gv[t] = fmaxf(s0, 0.f);
  __syncthreads();
  if (t < 50) {
    float s = hb1[h * 50 + t];
    for (int k = 0; k < 64; ++k) s += gv[k] * hW1[h * 3200 + k * 50 + t];
    h1[t] = fmaxf(s, 0.f);
  }
  __syncthreads();
  if (t < 25) {
    float s = hb2[h * 25 + t];
    for (int k = 0; k < 50; ++k) s += h1[k] * hW2[h * 1250 + k * 25 + t];
    h2[t] = fmaxf(s, 0.f);
  }
  __syncthreads();
  if (t == 0) {
    float s = hb3[h];
    for (int k = 0; k < 25; ++k) s += h2[k] * hW3[h * 25 + k];
    out[g * NHEADS + h] = s;
  }
}

// ------------------------------------------------------------------ launcher
extern "C" void kernel_launch(void* const* d_in, const int* in_sizes, int n_in,
                              void* d_out, int out_size, void* d_ws, size_t ws_size,
                              hipStream_t stream) {
  const float* x0    = (const float*)d_in[0];
  const int*   eidx  = (const int*)d_in[1];
  const int*   batch = (const int*)d_in[2];
  const float* dh    = (const float*)d_in[3];
  const float* preW  = (const float*)d_in[4];
  const float* preb  = (const float*)d_in[5];
  const float* postW = (const float*)d_in[6];
  const float* postb = (const float*)d_in[7];
  const float* linW  = (const float*)d_in[8];
  const float* linb  = (const float*)d_in[9];
  const float* bng   = (const float*)d_in[10];
  const float* bnb   = (const float*)d_in[11];
  const float* shW   = (const float*)d_in[12];
  const float* shb   = (const float*)d_in[13];
  const float* hW1   = (const float*)d_in[14];
  const float* hb1   = (const float*)d_in[15];
  const float* hW2   = (const float*)d_in[16];
  const float* hb2   = (const float*)d_in[17];
  const float* hW3   = (const float*)d_in[18];
  const float* hb3   = (const float*)d_in[19];
  float* out = (float*)d_out;

  char* ws = (char*)d_ws;
  size_t o = 0;
  auto alloc = [&](size_t bytes) {
    char* p = ws + o;
    o = (o + bytes + 255) & ~(size_t)255;
    return p;
  };
  float* scal   = (float*)alloc(8 * 4);
  int* off      = (int*)alloc((N_NODES + 1) * 4);
  int* cnt      = (int*)alloc(N_NODES * 4);
  int* esrc     = (int*)alloc(N_EDGES * 4);
  int* pairS    = (int*)alloc(N_EDGES * 4);
  unsigned char* pairDL = (unsigned char*)alloc(N_EDGES);
  int* wincur   = (int*)alloc(NWIN * 4);
  int* blks     = (int*)alloc(64 * 4);
  int* blko     = (int*)alloc(64 * 4);
  _Float16* A16    = (_Float16*)alloc((size_t)N_NODES * 64 * 2 + 256 * 16);
  _Float16* B16    = (_Float16*)alloc((size_t)N_NODES * 64 * 2 + 256 * 16);
  _Float16* aggr16 = (_Float16*)alloc((size_t)N_NODES * 256 * 2 + 256 * 16);
  _Float16* x16a   = (_Float16*)alloc((size_t)N_NODES * 64 * 2 + 256 * 16);
  _Float16* xbuf   = (_Float16*)alloc((size_t)N_NODES * 64 * 2 + 256 * 16);
  _Float16* y16    = (_Float16*)alloc((size_t)N_NODES * 64 * 2 + 256 * 16);
  float4* scales = (float4*)alloc((size_t)N_NODES * 16);
  _Float16* preP   = (_Float16*)alloc(3 * 8192 * 2);
  _Float16* postAP = (_Float16*)alloc((size_t)3 * 65536 * 2);
  _Float16* postBP = (_Float16*)alloc(3 * 4096 * 2);
  _Float16* linP   = (_Float16*)alloc(3 * 4096 * 2);
  float* part   = (float*)alloc(3 * 128 * 64 * 4);   // per-layer BN partials
  float* partq  = (float*)alloc(3 * 128 * 64 * 4);
  float* gsum   = (float*)alloc(NGRAPHS * 64 * 4);
  float* gcnt   = (float*)alloc(NGRAPHS * 4);

  const int* srcv = eidx;
  const int* dstv = eidx + N_EDGES;

  k_zero_setup<<<256, 256, 0, stream>>>(cnt, gsum, gcnt, part, partq, dh, in_sizes[3], scal);
  k_hist<<<(N_EDGES + 255) / 256, 256, 0, stream>>>(dstv, cnt);
  k_scan_a<<<49, 256, 0, stream>>>(cnt, off, blks);
  k_scan_b<<<1, 64, 0, stream>>>(blks, blko);
  k_scan_c<<<196, 256, 0, stream>>>(off, blko, wincur);
  k_part1<<<(N_EDGES + 2047) / 2048, 256, 0, stream>>>(srcv, dstv, wincur, pairS, pairDL);
  k_part2<<<NWIN, 256, 0, stream>>>(off, pairS, pairDL, esrc);
  k_prep<<<(400000 + 245760 + 255) / 256, 256, 0, stream>>>(x0, x16a, preW, postW, linW,
                                                            preP, postAP, postBP, linP);

  for (int l = 0; l < 3; ++l) {
    const _Float16* g1in = (l == 0) ? x16a : y16;
    const _Float16* xc   = (l == 0) ? x16a : xbuf;
    const float* partP  = part + (size_t)(l == 0 ? 0 : l - 1) * 8192;
    const float* partqP = partq + (size_t)(l == 0 ? 0 : l - 1) * 8192;
    k_mfma_g1<<<782, 256, 0, stream>>>(g1in, partP, partqP,
                                       bng + (l == 0 ? 0 : (l - 1) * 64), bnb + (l == 0 ? 0 : (l - 1) * 64),
                                       (l > 0) ? 1 : 0,
                                       preP + (size_t)l * 8192, preb + l * 64, A16, B16, xbuf);
    k_aggr<<<12544, 256, 0, stream>>>(A16, B16, off, esrc, scal, aggr16, scales);
    k_mfma_g23<<<782, 256, 0, stream>>>(aggr16, xc, postAP + (size_t)l * 65536,
                                        postBP + (size_t)l * 4096, postb + l * 64, scales,
                                        linP + (size_t)l * 4096, linb + l * 64, y16,
                                        part + (size_t)l * 8192, partq + (size_t)l * 8192);
  }
  k_pool<<<782, 256, 0, stream>>>(y16, part + 2 * 8192, partq + 2 * 8192,
                                  bng + 2 * 64, bnb + 2 * 64, batch, gsum, gcnt);
  k_sharedheads<<<NGRAPHS * NHEADS, 64, 0, stream>>>(gsum, gcnt, shW, shb,
                                                     hW1, hb1, hW2, hb2, hW3, hb3, out);
}

// Round 17
// 430.425 us; speedup vs baseline: 1.0476x; 1.0476x over previous
//
#include <hip/hip_runtime.h>
#include <math.h>

#define N_NODES 50000
#define N_EDGES 800000
#define NGRAPHS 50
#define NHEADS 3
#define EPS 1e-5f
#define NWIN 196      // fine windows of 256 nodes: win = dst >> 8
#define WSH 8

typedef _Float16 half8 __attribute__((ext_vector_type(8)));
typedef _Float16 half2v __attribute__((ext_vector_type(2)));
typedef float f32x4 __attribute__((ext_vector_type(4)));

__device__ inline half2v h2_shfl_xor(half2v v, int m) {
  int xi = __shfl_xor(*(int*)&v, m, 64);
  return *(half2v*)&xi;
}

// ------------------------------------------------------------------ setup (+folded scalars)
__global__ void __launch_bounds__(256) k_zero_setup(int* cnt, float* gsum, float* gcnt,
                                                    float* part, float* partq,
                                                    const float* dh, int nbins, float* scal) {
  int gid = blockIdx.x * 256 + threadIdx.x;
  int gs = gridDim.x * 256;
  for (int i = gid; i < N_NODES; i += gs) cnt[i] = 0;
  for (int i = gid; i < NGRAPHS * 64; i += gs) gsum[i] = 0.f;
  for (int i = gid; i < NGRAPHS; i += gs) gcnt[i] = 0.f;
  for (int i = gid; i < 3 * 128 * 64; i += gs) { part[i] = 0.f; partq[i] = 0.f; }
  if (blockIdx.x == 0 && threadIdx.x < 64) {
    int t = threadIdx.x;
    float v = (t < nbins) ? dh[t] : 0.f;
    float lv = logf((float)t + 1.f) * v;
    float bv = (float)t * v;
    for (int d = 32; d > 0; d >>= 1) {
      v  += __shfl_down(v,  d, 64);
      lv += __shfl_down(lv, d, 64);
      bv += __shfl_down(bv, d, 64);
    }
    if (t == 0) { scal[0] = lv / v; scal[1] = bv / v; }  // avg_log, avg_lin
  }
}

__global__ void __launch_bounds__(256) k_hist(const int* __restrict__ dst, int* __restrict__ cnt) {
  int e = blockIdx.x * 256 + threadIdx.x;
  if (e < N_EDGES) atomicAdd(&cnt[dst[e]], 1);
}

__global__ void __launch_bounds__(256) k_scan_a(const int* __restrict__ cnt, int* __restrict__ off,
                                                int* __restrict__ blksum) {
  __shared__ int lds[256];
  int t = threadIdx.x;
  int base = blockIdx.x * 1024 + t * 4;
  int v0 = (base + 0 < N_NODES) ? cnt[base + 0] : 0;
  int v1 = (base + 1 < N_NODES) ? cnt[base + 1] : 0;
  int v2 = (base + 2 < N_NODES) ? cnt[base + 2] : 0;
  int v3 = (base + 3 < N_NODES) ? cnt[base + 3] : 0;
  int tsum = v0 + v1 + v2 + v3;
  lds[t] = tsum; __syncthreads();
  for (int d = 1; d < 256; d <<= 1) {
    int x = (t >= d) ? lds[t - d] : 0;
    __syncthreads();
    lds[t] += x;
    __syncthreads();
  }
  int run = lds[t] - tsum;
  if (base + 0 < N_NODES) off[base + 0] = run; run += v0;
  if (base + 1 < N_NODES) off[base + 1] = run; run += v1;
  if (base + 2 < N_NODES) off[base + 2] = run; run += v2;
  if (base + 3 < N_NODES) off[base + 3] = run;
  if (t == 255) blksum[blockIdx.x] = lds[255];
}

__global__ void __launch_bounds__(64) k_scan_b(const int* __restrict__ blksum, int* __restrict__ blkoff) {
  int t = threadIdx.x;
  int own = (t < 49) ? blksum[t] : 0;
  int v = own;
  for (int d = 1; d < 64; d <<= 1) {
    int u = __shfl_up(v, d, 64);
    if (t >= d) v += u;
  }
  if (t < 49) blkoff[t] = v - own;
}

__global__ void __launch_bounds__(256) k_scan_c(int* __restrict__ off, const int* __restrict__ blkoff,
                                                int* __restrict__ wincur) {
  int i = blockIdx.x * 256 + threadIdx.x;
  if (i < N_NODES) {
    int fo = off[i] + blkoff[i >> 10];
    off[i] = fo;
    if ((i & 255) == 0) wincur[i >> WSH] = fo;
  }
  if (i == 0) off[N_NODES] = N_EDGES;
}

// ---------------- phase 1: LDS-compact partition into 196 fine windows ----------------
__global__ void __launch_bounds__(256) k_part1(const int* __restrict__ src, const int* __restrict__ dst,
                                               int* __restrict__ wincur, int* __restrict__ pairS,
                                               unsigned char* __restrict__ pairDL) {
  __shared__ int hist[256];
  __shared__ int scan[256];
  __shared__ int baseg[256];
  __shared__ int place[256];
  __shared__ int sS[2048];
  __shared__ unsigned char sDL[2048];
  __shared__ unsigned char sW[2048];
  int t = threadIdx.x;
  int base = blockIdx.x * 2048;
  hist[t] = 0;
  __syncthreads();
  int d[8], s[8];
  #pragma unroll
  for (int i = 0; i < 8; ++i) {
    int e = base + t + 256 * i;
    bool val = e < N_EDGES;
    d[i] = val ? dst[e] : -1;
    s[i] = val ? src[e] : 0;
    if (val) atomicAdd(&hist[d[i] >> WSH], 1);
  }
  __syncthreads();
  int v = hist[t];
  scan[t] = v; __syncthreads();
  for (int dd = 1; dd < 256; dd <<= 1) {
    int x = (t >= dd) ? scan[t - dd] : 0;
    __syncthreads();
    scan[t] += x;
    __syncthreads();
  }
  place[t] = scan[t] - v;
  if (v > 0) baseg[t] = atomicAdd(&wincur[t], v);
  __syncthreads();
  #pragma unroll
  for (int i = 0; i < 8; ++i) {
    if (d[i] >= 0) {
      int w = d[i] >> WSH;
      int p = atomicAdd(&place[w], 1);
      sS[p] = s[i] << 7;           // byte offset into B [N,64] fp16 (128 B rows)
      sDL[p] = (unsigned char)(d[i] & 255);
      sW[p] = (unsigned char)w;
    }
  }
  __syncthreads();
  int tot = min(N_EDGES - base, 2048);
  for (int i = t; i < tot; i += 256) {
    int w = sW[i];
    int gidx = baseg[w] + (i - (scan[w] - hist[w]));
    pairS[gidx] = sS[i];
    pairDL[gidx] = sDL[i];
  }
}

// ---------------- phase 2: per-window LDS-resident CSR scatter, coalesced flush ----------------
__global__ void __launch_bounds__(256) k_part2(const int* __restrict__ off, const int* __restrict__ pairS,
                                               const unsigned char* __restrict__ pairDL,
                                               int* __restrict__ esrc) {
  __shared__ int curW[256];
  __shared__ int offW[257];
  __shared__ int esrcW[6144];
  int w = blockIdx.x, t = threadIdx.x;
  int n0 = w << WSH;
  offW[t] = off[min(n0 + t, N_NODES)];
  if (t == 0) offW[256] = off[min(n0 + 256, N_NODES)];
  curW[t] = 0;
  __syncthreads();
  int start = offW[0];
  int end = offW[256];
  int cnt = end - start;
  if (cnt <= 6144) {
    for (int i = t; i < cnt; i += 256) {
      int s = pairS[start + i];
      int dl = pairDL[start + i];
      int pos = offW[dl] - start + atomicAdd(&curW[dl], 1);
      esrcW[pos] = s;
    }
    __syncthreads();
    for (int i = t; i < cnt; i += 256) esrc[start + i] = esrcW[i];
  } else {
    for (int i = t; i < cnt; i += 256) {
      int s = pairS[start + i];
      int dl = pairDL[start + i];
      int pos = offW[dl] + atomicAdd(&curW[dl], 1);
      esrc[pos] = s;
    }
  }
}

// ------------------------------------------------------------------ f2h + weight packing (b-frag order)
__global__ void __launch_bounds__(256) k_prep(const float* __restrict__ xin, _Float16* __restrict__ xout,
                                              const float* __restrict__ preW, const float* __restrict__ postW,
                                              const float* __restrict__ linW, _Float16* __restrict__ preP,
                                              _Float16* __restrict__ postAP, _Float16* __restrict__ postBP,
                                              _Float16* __restrict__ linP) {
  int t0 = blockIdx.x * 256 + threadIdx.x;
  if (t0 < 400000) {
    const float* s = xin + (size_t)t0 * 8;
    float4 v0 = *(const float4*)s;
    float4 v1 = *(const float4*)(s + 4);
    half8 h = {(_Float16)v0.x, (_Float16)v0.y, (_Float16)v0.z, (_Float16)v0.w,
               (_Float16)v1.x, (_Float16)v1.y, (_Float16)v1.z, (_Float16)v1.w};
    *(half8*)(xout + (size_t)t0 * 8) = h;
    return;
  }
  int t = t0 - 400000;
  if (t < 24576) {  // preP: 3 * 8192
    int l = t >> 13, r = t & 8191;
    int j = r & 7, lane = (r >> 3) & 63, ctg = (r >> 9) & 7, kc = r >> 12;
    int k = kc * 32 + ((lane >> 4) << 3) + j;
    int col = ctg * 16 + (lane & 15);
    const float* W = preW + (size_t)l * 8192;
    float v = (col < 64) ? W[k * 64 + col] : W[(64 + k) * 64 + (col - 64)];
    preP[(size_t)l * 8192 + r] = (_Float16)v;
  } else if (t < 221184) {  // postAP: 3 * 65536 (aggr K plain order: mean|min|max|std)
    int q = t - 24576;
    int l = q >> 16, r = q & 65535;
    int j = r & 7, lane = (r >> 3) & 63, ct = (r >> 9) & 3, s = (r >> 11) & 3, kc = r >> 13;
    int k = kc * 32 + ((lane >> 4) << 3) + j;
    int col = ct * 16 + (lane & 15);
    postAP[(size_t)l * 65536 + r] = (_Float16)postW[(size_t)l * 69632 + (size_t)(64 + s * 256 + k) * 64 + col];
  } else if (t < 233472) {  // postBP: 3 * 4096
    int q = t - 221184;
    int l = q >> 12, r = q & 4095;
    int j = r & 7, lane = (r >> 3) & 63, ct = (r >> 9) & 3, kc = r >> 11;
    int k = kc * 32 + ((lane >> 4) << 3) + j;
    int col = ct * 16 + (lane & 15);
    postBP[(size_t)l * 4096 + r] = (_Float16)postW[(size_t)l * 69632 + (size_t)k * 64 + col];
  } else if (t < 245760) {  // linP: 3 * 4096
    int q = t - 233472;
    int l = q >> 12, r = q & 4095;
    int j = r & 7, lane = (r >> 3) & 63, ct = (r >> 9) & 3, kc = r >> 11;
    int k = kc * 32 + ((lane >> 4) << 3) + j;
    int col = ct * 16 + (lane & 15);
    linP[(size_t)l * 4096 + r] = (_Float16)linW[(size_t)l * 4096 + (size_t)k * 64 + col];
  }
}

// ------------------------------------------------------------------ GEMM1 (+fused BN coefficient computation
// from per-layer part/partq + BN-apply of previous layer). Writes A [N,64] and B [N,64].
__global__ void __launch_bounds__(256) k_mfma_g1(const _Float16* __restrict__ yin,
                                                 const float* __restrict__ part, const float* __restrict__ partq,
                                                 const float* __restrict__ bng, const float* __restrict__ bnb,
                                                 int applyBN,
                                                 const _Float16* __restrict__ wp, const float* __restrict__ bias,
                                                 _Float16* __restrict__ Aout, _Float16* __restrict__ Bout,
                                                 _Float16* __restrict__ xout) {
  __shared__ float ls[256], lq[256];
  __shared__ __align__(16) float scS[64], shS[64];
  int t = threadIdx.x, lane = t & 63, wave = t >> 6;
  int r0 = blockIdx.x * 64;
  int mrow = lane & 15, q8 = ((lane >> 4) << 3);
  if (applyBN) {
    int col = t & 63, qtr = t >> 6;
    float s = 0.f, q = 0.f;
    for (int i = 0; i < 32; ++i) {
      int slot = qtr * 32 + i;
      s += part[slot * 64 + col];
      q += partq[slot * 64 + col];
    }
    ls[t] = s; lq[t] = q; __syncthreads();
    if (t < 64) {
      s = ls[t] + ls[64 + t] + ls[128 + t] + ls[192 + t];
      q = lq[t] + lq[64 + t] + lq[128 + t] + lq[192 + t];
      float m = s / (float)N_NODES;
      float v = fmaxf(q / (float)N_NODES - m * m, 0.f);
      float sc = bng[t] * rsqrtf(v + EPS);
      scS[t] = sc;
      shS[t] = bnb[t] - m * sc;
    }
    __syncthreads();
  }
  f32x4 acc[4][2];
  #pragma unroll
  for (int rt = 0; rt < 4; ++rt) { acc[rt][0] = (f32x4)0.f; acc[rt][1] = (f32x4)0.f; }
  #pragma unroll
  for (int kc = 0; kc < 2; ++kc) {
    int k0 = kc * 32 + q8;
    half8 a[4];
    #pragma unroll
    for (int rt = 0; rt < 4; ++rt) {
      int r = min(r0 + rt * 16 + mrow, N_NODES - 1);
      a[rt] = *(const half8*)(yin + (size_t)r * 64 + k0);
    }
    if (applyBN) {
      float4 sc0 = *(const float4*)(scS + k0);
      float4 sc1 = *(const float4*)(scS + k0 + 4);
      float4 sh0 = *(const float4*)(shS + k0);
      float4 sh1 = *(const float4*)(shS + k0 + 4);
      #pragma unroll
      for (int rt = 0; rt < 4; ++rt) {
        half8 v = a[rt];
        v[0] = (_Float16)fmaxf((float)v[0] * sc0.x + sh0.x, 0.f);
        v[1] = (_Float16)fmaxf((float)v[1] * sc0.y + sh0.y, 0.f);
        v[2] = (_Float16)fmaxf((float)v[2] * sc0.z + sh0.z, 0.f);
        v[3] = (_Float16)fmaxf((float)v[3] * sc0.w + sh0.w, 0.f);
        v[4] = (_Float16)fmaxf((float)v[4] * sc1.x + sh1.x, 0.f);
        v[5] = (_Float16)fmaxf((float)v[5] * sc1.y + sh1.y, 0.f);
        v[6] = (_Float16)fmaxf((float)v[6] * sc1.z + sh1.z, 0.f);
        v[7] = (_Float16)fmaxf((float)v[7] * sc1.w + sh1.w, 0.f);
        a[rt] = v;
      }
      if (wave == 0) {
        #pragma unroll
        for (int rt = 0; rt < 4; ++rt) {
          int r = min(r0 + rt * 16 + mrow, N_NODES - 1);
          *(half8*)(xout + (size_t)r * 64 + k0) = a[rt];
        }
      }
    }
    #pragma unroll
    for (int ci = 0; ci < 2; ++ci) {
      int ctg = wave * 2 + ci;
      half8 b = *(const half8*)(wp + (size_t)((kc * 8 + ctg) * 64 + lane) * 8);
      #pragma unroll
      for (int rt = 0; rt < 4; ++rt)
        acc[rt][ci] = __builtin_amdgcn_mfma_f32_16x16x32_f16(a[rt], b, acc[rt][ci], 0, 0, 0);
    }
  }
  #pragma unroll
  for (int ci = 0; ci < 2; ++ci) {
    int col = (wave * 2 + ci) * 16 + mrow;
    bool isA = col < 64;
    float bv = isA ? bias[col] : 0.f;
    _Float16* outp = isA ? (Aout + col) : (Bout + (col - 64));
    #pragma unroll
    for (int rt = 0; rt < 4; ++rt)
      #pragma unroll
      for (int reg = 0; reg < 4; ++reg) {
        int row = r0 + rt * 16 + ((lane >> 4) << 2) + reg;
        if (row < N_NODES) outp[(size_t)row * 64] = (_Float16)(acc[rt][ci][reg] + bv);
      }
  }
}

// ------------------------------------------------------------------ aggregation: single pass, full 64 features
// 32 lanes/edge x 2 packed features; esrc = src*128 byte offsets into B [N,64].
// Fully predicated 16-edge-wide loop; linear block->node mapping.
__global__ void __launch_bounds__(256) k_aggr(const _Float16* __restrict__ A, const _Float16* __restrict__ B,
                                              const int* __restrict__ off, const int* __restrict__ esrc,
                                              const float* __restrict__ scal, _Float16* __restrict__ aggr,
                                              float4* __restrict__ scales) {
  int wave = threadIdx.x >> 6, lane = threadIdx.x & 63;
  int n = blockIdx.x * 4 + wave;
  int lh = lane & 31, eg = lane >> 5;
  half2v c2 = *(const half2v*)(A + (size_t)n * 64 + lh * 2);
  int e0 = __builtin_amdgcn_readfirstlane(off[n]);
  int e1 = __builtin_amdgcn_readfirstlane(off[n + 1]);
  int deg = e1 - e0;
  const char* Bb = (const char*)B;
  int lo4 = lh * 4;
  const _Float16 HMAX = (_Float16)65504.f;
  half2v z2 = {(_Float16)0.f, (_Float16)0.f};
  half2v p2 = {HMAX, HMAX};
  half2v m2v = {-HMAX, -HMAX};
  half2v s2 = z2, q2 = z2, mn2 = p2, mx2 = m2v;
  if (deg > 0) {
    int e1m1 = e1 - 1;
    for (int e = e0; e < e1; e += 16) {
      int ro[8];
      #pragma unroll
      for (int g = 0; g < 8; ++g)
        ro[g] = esrc[min(e + g * 2 + eg, e1m1)];
      half2v v[8];
      #pragma unroll
      for (int g = 0; g < 8; ++g)
        v[g] = *(const half2v*)(Bb + ro[g] + lo4);
      #pragma unroll
      for (int g = 0; g < 8; ++g) {
        bool valid = (e + g * 2 + eg) < e1;
        half2v vm = valid ? v[g] : z2;
        s2 += vm;
        q2 += vm * vm;
        mn2 = __builtin_elementwise_min(mn2, valid ? v[g] : p2);
        mx2 = __builtin_elementwise_max(mx2, valid ? v[g] : m2v);
      }
    }
  }
  s2 += h2_shfl_xor(s2, 32);
  q2 += h2_shfl_xor(q2, 32);
  mn2 = __builtin_elementwise_min(mn2, h2_shfl_xor(mn2, 32));
  mx2 = __builtin_elementwise_max(mx2, h2_shfl_xor(mx2, 32));
  if (eg == 0) {
    _Float16* arow = aggr + (size_t)n * 256;
    half2v w;
    if (deg == 0) {
      w = z2;
      *(half2v*)(arow + lh * 2) = w;
      *(half2v*)(arow + 64 + lh * 2) = w;
      *(half2v*)(arow + 128 + lh * 2) = w;
      w[0] = (_Float16)sqrtf(EPS); w[1] = w[0];
      *(half2v*)(arow + 192 + lh * 2) = w;
    } else {
      float c0 = (float)c2[0], c1 = (float)c2[1];
      float inv = 1.f / (float)deg;
      float mb0 = (float)s2[0] * inv, mb1 = (float)s2[1] * inv;
      float v0 = fmaxf((float)q2[0] * inv - mb0 * mb0, 0.f);
      float v1 = fmaxf((float)q2[1] * inv - mb1 * mb1, 0.f);
      w[0] = (_Float16)(c0 + mb0); w[1] = (_Float16)(c1 + mb1);
      *(half2v*)(arow + lh * 2) = w;
      w[0] = (_Float16)(c0 + (float)mn2[0]); w[1] = (_Float16)(c1 + (float)mn2[1]);
      *(half2v*)(arow + 64 + lh * 2) = w;
      w[0] = (_Float16)(c0 + (float)mx2[0]); w[1] = (_Float16)(c1 + (float)mx2[1]);
      *(half2v*)(arow + 128 + lh * 2) = w;
      w[0] = (_Float16)sqrtf(v0 + EPS); w[1] = (_Float16)sqrtf(v1 + EPS);
      *(half2v*)(arow + 192 + lh * 2) = w;
    }
    if (lane == 0) {
      float degf = fmaxf((float)deg, 1.f);
      float ld = logf(degf + 1.f);
      float al = scal[0], av = scal[1];
      scales[n] = make_float4(ld / al, al / ld, degf / av, 0.f);
    }
  }
}

// ------------------------------------------------------------------ FUSED GEMM2 + GEMM3 (+BN partial stats)
// 32-row tiles (1563 blocks) + full load prefetch: all 16 aggr + 4 x16 loads issued
// before any MFMA -> single vmcnt-pipelined phase instead of 4 serial load-waits.
__global__ void __launch_bounds__(256) k_mfma_g23(const _Float16* __restrict__ aggr,
                                                  const _Float16* __restrict__ x16,
                                                  const _Float16* __restrict__ wpA, const _Float16* __restrict__ wpB,
                                                  const float* __restrict__ postb, const float4* __restrict__ scales,
                                                  const _Float16* __restrict__ linP, const float* __restrict__ linb,
                                                  _Float16* __restrict__ y16,
                                                  float* __restrict__ part, float* __restrict__ partq) {
  __shared__ _Float16 yS[32][72];
  int t = threadIdx.x, lane = t & 63, ct = t >> 6;
  int r0 = blockIdx.x * 32;
  int mrow = lane & 15, q8 = ((lane >> 4) << 3);
  int r[2];
  #pragma unroll
  for (int rt = 0; rt < 2; ++rt) r[rt] = min(r0 + rt * 16 + mrow, N_NODES - 1);
  // ---- prefetch ALL aggr + x16 loads (issued back-to-back; MFMAs pipeline on vmcnt)
  half8 a[8][2];
  #pragma unroll
  for (int kc = 0; kc < 8; ++kc)
    #pragma unroll
    for (int rt = 0; rt < 2; ++rt)
      a[kc][rt] = *(const half8*)(aggr + (size_t)r[rt] * 256 + kc * 32 + q8);
  half8 ax[2][2];
  #pragma unroll
  for (int kc = 0; kc < 2; ++kc)
    #pragma unroll
    for (int rt = 0; rt < 2; ++rt)
      ax[kc][rt] = *(const half8*)(x16 + (size_t)r[rt] * 64 + kc * 32 + q8);
  f32x4 acc[2][4];  // [rowtile][set]
  #pragma unroll
  for (int rt = 0; rt < 2; ++rt)
    #pragma unroll
    for (int s = 0; s < 4; ++s) acc[rt][s] = (f32x4)0.f;
  #pragma unroll
  for (int kc = 0; kc < 8; ++kc) {
    #pragma unroll
    for (int s = 0; s < 4; ++s) {
      half8 b = *(const half8*)(wpA + (size_t)((((kc * 4 + s) * 4 + ct) * 64) + lane) * 8);
      #pragma unroll
      for (int rt = 0; rt < 2; ++rt)
        acc[rt][s] = __builtin_amdgcn_mfma_f32_16x16x32_f16(a[kc][rt], b, acc[rt][s], 0, 0, 0);
    }
  }
  #pragma unroll
  for (int kc = 0; kc < 2; ++kc) {
    half8 b = *(const half8*)(wpB + (size_t)(((kc * 4 + ct) * 64) + lane) * 8);
    #pragma unroll
    for (int rt = 0; rt < 2; ++rt)
      acc[rt][0] = __builtin_amdgcn_mfma_f32_16x16x32_f16(ax[kc][rt], b, acc[rt][0], 0, 0, 0);
  }
  int col = ct * 16 + mrow;
  float pb = postb[col];
  #pragma unroll
  for (int rt = 0; rt < 2; ++rt)
    #pragma unroll
    for (int reg = 0; reg < 4; ++reg) {
      int rr = rt * 16 + ((lane >> 4) << 2) + reg;
      int row = min(r0 + rr, N_NODES - 1);
      float4 sc = scales[row];
      float v = acc[rt][0][reg] + sc.x * acc[rt][1][reg] + sc.y * acc[rt][2][reg] + sc.z * acc[rt][3][reg] + pb;
      yS[rr][col] = (_Float16)v;
    }
  __syncthreads();
  // ---- GEMM3 from LDS
  f32x4 acc2[2];
  #pragma unroll
  for (int rt = 0; rt < 2; ++rt) acc2[rt] = (f32x4)0.f;
  #pragma unroll
  for (int kc = 0; kc < 2; ++kc) {
    half8 av[2];
    #pragma unroll
    for (int rt = 0; rt < 2; ++rt)
      av[rt] = *(const half8*)(&yS[rt * 16 + mrow][kc * 32 + q8]);
    half8 b = *(const half8*)(linP + (size_t)(((kc * 4 + ct) * 64) + lane) * 8);
    #pragma unroll
    for (int rt = 0; rt < 2; ++rt)
      acc2[rt] = __builtin_amdgcn_mfma_f32_16x16x32_f16(av[rt], b, acc2[rt], 0, 0, 0);
  }
  float bv = linb[col];
  float s = 0.f, q = 0.f;
  #pragma unroll
  for (int rt = 0; rt < 2; ++rt)
    #pragma unroll
    for (int reg = 0; reg < 4; ++reg) {
      int row = r0 + rt * 16 + ((lane >> 4) << 2) + reg;
      if (row < N_NODES) {
        float v = acc2[rt][reg] + bv;
        y16[(size_t)row * 64 + col] = (_Float16)v;
        s += v; q += v * v;
      }
    }
  // wave-reduce over the 4 lanes sharing each col (lane>>4) -> 1 atomic per col per wave
  s += __shfl_xor(s, 16, 64); s += __shfl_xor(s, 32, 64);
  q += __shfl_xor(q, 16, 64); q += __shfl_xor(q, 32, 64);
  if ((lane >> 4) == 0) {
    int slot = (blockIdx.x & 127) * 64 + col;
    atomicAdd(&part[slot], s);
    atomicAdd(&partq[slot], q);
  }
}

// ------------------------------------------------------------------ pooling (+fused BN coeffs + final BN)
__global__ void __launch_bounds__(256) k_pool(const _Float16* __restrict__ y16,
                                              const float* __restrict__ part, const float* __restrict__ partq,
                                              const float* __restrict__ bng, const float* __restrict__ bnb,
                                              const int* __restrict__ batch,
                                              float* __restrict__ gsum, float* __restrict__ gcnt) {
  __shared__ float ls[256], lq[256];
  __shared__ float scS[64], shS[64];
  int t = threadIdx.x, col = t & 63, rl = t >> 6;
  {
    float s = 0.f, q = 0.f;
    for (int i = 0; i < 32; ++i) {
      int slot = rl * 32 + i;
      s += part[slot * 64 + col];
      q += partq[slot * 64 + col];
    }
    ls[t] = s; lq[t] = q; __syncthreads();
    if (t < 64) {
      s = ls[t] + ls[64 + t] + ls[128 + t] + ls[192 + t];
      q = lq[t] + lq[64 + t] + lq[128 + t] + lq[192 + t];
      float m = s / (float)N_NODES;
      float v = fmaxf(q / (float)N_NODES - m * m, 0.f);
      float sc = bng[t] * rsqrtf(v + EPS);
      scS[t] = sc;
      shS[t] = bnb[t] - m * sc;
    }
    __syncthreads();
  }
  float sc = scS[col], sh = shS[col];
  int rbeg = blockIdx.x * 64 + rl * 16;
  int rend = min(rbeg + 16, N_NODES);
  int curg = -1, cr = 0;
  float acc = 0.f;
  for (int r = rbeg; r < rend; ++r) {
    int g = batch[r];
    if (g != curg) {
      if (curg >= 0) {
        atomicAdd(&gsum[curg * 64 + col], acc);
        if (col == 0) atomicAdd(&gcnt[curg], (float)cr);
      }
      curg = g; acc = 0.f; cr = 0;
    }
    acc += fmaxf((float)y16[(size_t)r * 64 + col] * sc + sh, 0.f); cr++;
  }
  if (curg >= 0) {
    atomicAdd(&gsum[curg * 64 + col], acc);
    if (col == 0) atomicAdd(&gcnt[curg], (float)cr);
  }
}

// ------------------------------------------------------------------ shared MLP + heads fused
__global__ void __launch_bounds__(64) k_sharedheads(const float* __restrict__ gsum, const float* __restrict__ gcnt,
                                                    const float* __restrict__ W, const float* __restrict__ b,
                                                    const float* __restrict__ hW1, const float* __restrict__ hb1,
                                                    const float* __restrict__ hW2, const float* __restrict__ hb2,
                                                    const float* __restrict__ hW3, const float* __restrict__ hb3,
                                                    float* __restrict__ out) {
  __shared__ float gm[64], gv[64], h1[50], h2[25];
  int bid = blockIdx.x;
  int g = bid / NHEADS, h = bid % NHEADS;
  int t = threadIdx.x;
  float cv = fmaxf(gcnt[g], 1.f);
  gm[t] = gsum[g * 64 + t] / cv;
  __syncthreads();
  float s0 = b[t];
  for (int k = 0; k < 64; ++k) s0 += gm[k] * W[k * 64 + t];
  gv[t] = fmaxf(s0, 0.f);
  __syncthreads();
  if (t < 50) {
    float s = hb1[h * 50 + t];
    for (int k = 0; k < 64; ++k) s += gv[k] * hW1[h * 3200 + k * 50 + t];
    h1[t] = fmaxf(s, 0.f);
  }
  __syncthreads();
  if (t < 25) {
    float s = hb2[h * 25 + t];
    for (int k = 0; k < 50; ++k) s += h1[k] * hW2[h * 1250 + k * 25 + t];
    h2[t] = fmaxf(s, 0.f);
  }
  __syncthreads();
  if (t == 0) {
    float s = hb3[h];
    for (int k = 0; k < 25; ++k) s += h2[k] * hW3[h * 25 + k];
    out[g * NHEADS + h] = s;
  }
}

// ------------------------------------------------------------------ launcher
extern "C" void kernel_launch(void* const* d_in, const int* in_sizes, int n_in,
                              void* d_out, int out_size, void* d_ws, size_t ws_size,
                              hipStream_t stream) {
  const float* x0    = (const float*)d_in[0];
  const int*   eidx  = (const int*)d_in[1];
  const int*   batch = (const int*)d_in[2];
  const float* dh    = (const float*)d_in[3];
  const float* preW  = (const float*)d_in[4];
  const float* preb  = (const float*)d_in[5];
  const float* postW = (const float*)d_in[6];
  const float* postb = (const float*)d_in[7];
  const float* linW  = (const float*)d_in[8];
  const float* linb  = (const float*)d_in[9];
  const float* bng   = (const float*)d_in[10];
  const float* bnb   = (const float*)d_in[11];
  const float* shW   = (const float*)d_in[12];
  const float* shb   = (const float*)d_in[13];
  const float* hW1   = (const float*)d_in[14];
  const float* hb1   = (const float*)d_in[15];
  const float* hW2   = (const float*)d_in[16];
  const float* hb2   = (const float*)d_in[17];
  const float* hW3   = (const float*)d_in[18];
  const float* hb3   = (const float*)d_in[19];
  float* out = (float*)d_out;

  char* ws = (char*)d_ws;
  size_t o = 0;
  auto alloc = [&](size_t bytes) {
    char* p = ws + o;
    o = (o + bytes + 255) & ~(size_t)255;
    return p;
  };
  float* scal   = (float*)alloc(8 * 4);
  int* off      = (int*)alloc((N_NODES + 1) * 4);
  int* cnt      = (int*)alloc(N_NODES * 4);
  int* esrc     = (int*)alloc(N_EDGES * 4);
  int* pairS    = (int*)alloc(N_EDGES * 4);
  unsigned char* pairDL = (unsigned char*)alloc(N_EDGES);
  int* wincur   = (int*)alloc(NWIN * 4);
  int* blks     = (int*)alloc(64 * 4);
  int* blko     = (int*)alloc(64 * 4);
  _Float16* A16    = (_Float16*)alloc((size_t)N_NODES * 64 * 2 + 256 * 16);
  _Float16* B16    = (_Float16*)alloc((size_t)N_NODES * 64 * 2 + 256 * 16);
  _Float16* aggr16 = (_Float16*)alloc((size_t)N_NODES * 256 * 2 + 256 * 16);
  _Float16* x16a   = (_Float16*)alloc((size_t)N_NODES * 64 * 2 + 256 * 16);
  _Float16* xbuf   = (_Float16*)alloc((size_t)N_NODES * 64 * 2 + 256 * 16);
  _Float16* y16    = (_Float16*)alloc((size_t)N_NODES * 64 * 2 + 256 * 16);
  float4* scales = (float4*)alloc((size_t)N_NODES * 16);
  _Float16* preP   = (_Float16*)alloc(3 * 8192 * 2);
  _Float16* postAP = (_Float16*)alloc((size_t)3 * 65536 * 2);
  _Float16* postBP = (_Float16*)alloc(3 * 4096 * 2);
  _Float16* linP   = (_Float16*)alloc(3 * 4096 * 2);
  float* part   = (float*)alloc(3 * 128 * 64 * 4);   // per-layer BN partials
  float* partq  = (float*)alloc(3 * 128 * 64 * 4);
  float* gsum   = (float*)alloc(NGRAPHS * 64 * 4);
  float* gcnt   = (float*)alloc(NGRAPHS * 4);

  const int* srcv = eidx;
  const int* dstv = eidx + N_EDGES;

  k_zero_setup<<<256, 256, 0, stream>>>(cnt, gsum, gcnt, part, partq, dh, in_sizes[3], scal);
  k_hist<<<(N_EDGES + 255) / 256, 256, 0, stream>>>(dstv, cnt);
  k_scan_a<<<49, 256, 0, stream>>>(cnt, off, blks);
  k_scan_b<<<1, 64, 0, stream>>>(blks, blko);
  k_scan_c<<<196, 256, 0, stream>>>(off, blko, wincur);
  k_part1<<<(N_EDGES + 2047) / 2048, 256, 0, stream>>>(srcv, dstv, wincur, pairS, pairDL);
  k_part2<<<NWIN, 256, 0, stream>>>(off, pairS, pairDL, esrc);
  k_prep<<<(400000 + 245760 + 255) / 256, 256, 0, stream>>>(x0, x16a, preW, postW, linW,
                                                            preP, postAP, postBP, linP);

  for (int l = 0; l < 3; ++l) {
    const _Float16* g1in = (l == 0) ? x16a : y16;
    const _Float16* xc   = (l == 0) ? x16a : xbuf;
    const float* partP  = part + (size_t)(l == 0 ? 0 : l - 1) * 8192;
    const float* partqP = partq + (size_t)(l == 0 ? 0 : l - 1) * 8192;
    k_mfma_g1<<<782, 256, 0, stream>>>(g1in, partP, partqP,
                                       bng + (l == 0 ? 0 : (l - 1) * 64), bnb + (l == 0 ? 0 : (l - 1) * 64),
                                       (l > 0) ? 1 : 0,
                                       preP + (size_t)l * 8192, preb + l * 64, A16, B16, xbuf);
    k_aggr<<<12500, 256, 0, stream>>>(A16, B16, off, esrc, scal, aggr16, scales);
    k_mfma_g23<<<1563, 256, 0, stream>>>(aggr16, xc, postAP + (size_t)l * 65536,
                                         postBP + (size_t)l * 4096, postb + l * 64, scales,
                                         linP + (size_t)l * 4096, linb + l * 64, y16,
                                         part + (size_t)l * 8192, partq + (size_t)l * 8192);
  }
  k_pool<<<782, 256, 0, stream>>>(y16, part + 2 * 8192, partq + 2 * 8192,
                                  bng + 2 * 64, bnb + 2 * 64, batch, gsum, gcnt);
  k_sharedheads<<<NGRAPHS * NHEADS, 64, 0, stream>>>(gsum, gcnt, shW, shb,
                                                     hW1, hb1, hW2, hb2, hW3, hb3, out);
}